// Round 5
// baseline (844.408 us; speedup 1.0000x reference)
//
#include <hip/hip_runtime.h>
#include <hip/hip_bf16.h>
#include <stdint.h>

// Encoder: B=2,S=2048,D=1024,HID=1024,NH=16,C=64,L=4. 4096 token-rows.
#define TOK 4096
#define DM  1024

using u16 = unsigned short;
typedef __attribute__((ext_vector_type(8))) short short8;   // bf16x8 frag (4 VGPR)
typedef __attribute__((ext_vector_type(4))) float f32x4;

__device__ __forceinline__ u16 f2bf(float f){
  unsigned u = __float_as_uint(f);
  return (u16)((u + 0x7fffu + ((u >> 16) & 1u)) >> 16);   // RNE
}
__device__ __forceinline__ float bf2f(u16 h){ return __uint_as_float(((unsigned)h) << 16); }

// ---------------- pos-enc add: r = x + pe, xb = bf16(r) ----------------
__global__ __launch_bounds__(256) void posenc_add(
    const float* __restrict__ x, float* __restrict__ r, u16* __restrict__ xb)
{
  const int t = blockIdx.x;          // token row 0..4095
  const int s = t & 2047;            // seq position
  const size_t base = (size_t)t * DM;
#pragma unroll
  for (int i = 0; i < 4; ++i){
    const int d = threadIdx.x + i * 256;
    const float e = (float)(d & ~1) * (1.0f / (float)DM);
    const float denom = powf(1000.0f, e);
    const float mat = (float)s / denom;
    const float pe = (d & 1) ? cosf(mat) : sinf(mat);
    const float v = x[base + d] + pe;
    r[base + d] = v;
    xb[base + d] = f2bf(v);
  }
}

// ---------- weight transpose+cast: 6 matrices [1024][1024] f32 -> [N][K] bf16 ----------
// WT layout per layer: [0]=WqT [1]=WkT [2]=WvT (contiguous 3072x1024) [3]=WoT [4]=W1T [5]=W2T
// Multi-layer launch: bid = (l-l0)*6144 + mm*1024 + t   (6144 = 6*1024 blocks per layer)
__global__ __launch_bounds__(256) void transpose6(
    const float* __restrict__ Wq, const float* __restrict__ Wk, const float* __restrict__ Wv,
    const float* __restrict__ Wo, const float* __restrict__ W1, const float* __restrict__ W2,
    u16* __restrict__ WT, int l0)
{
  __shared__ float tile[32][33];
  const int bid = blockIdx.x;
  const int l  = l0 + bid / 6144;          // layer spans 6144 blocks
  const int mm = (bid >> 10) % 6;          // matrix 0..5 within layer
  const int t  = bid & 1023;
  const int tn = (t & 31) * 32;
  const int tk = (t >> 5) * 32;
  const float* src = (mm==0)?Wq:(mm==1)?Wk:(mm==2)?Wv:(mm==3)?Wo:(mm==4)?W1:W2;
  src += (size_t)l * 1048576;
  u16* dst = WT + ((size_t)(l - l0) * 6 + mm) * 1048576;
  const int tx = threadIdx.x & 31, ty = threadIdx.x >> 5;
#pragma unroll
  for (int i = 0; i < 4; ++i)
    tile[ty + i*8][tx] = src[(size_t)(tk + ty + i*8) * 1024 + tn + tx];
  __syncthreads();
#pragma unroll
  for (int i = 0; i < 4; ++i)
    dst[(size_t)(tn + ty + i*8) * 1024 + tk + tx] = f2bf(tile[tx][ty + i*8]);
}

// ---------------- bf16 MFMA GEMM: C[M][N] = A[M][1024] @ BT[N][1024]^T ----------------
// m97 structure: 128x128 tile, BK=64, single 32KB LDS, global_load_lds(16B),
// pre-swizzled global source + swizzled ds_read. Bijective XCD swizzle on grid.
// MODE 0: +bias -> bf16 out ; MODE 1: relu(+bias) -> bf16 ; MODE 2: qkv (bias triple, q*=0.125) -> bf16
#define BM 128
#define BN 128
#define BK 64
#define KD 1024

template<int MODE>
__global__ __launch_bounds__(256) void gemm_k1024(
    const u16* __restrict__ A, const u16* __restrict__ BT,
    const float* __restrict__ bias0, const float* __restrict__ bias1, const float* __restrict__ bias2,
    u16* __restrict__ outB, int M, int N)
{
  __shared__ __align__(16) u16 sA[BM*BK];   // linear rows of 128B; CONTENT swizzled
  __shared__ __align__(16) u16 sB[BN*BK];
  const int tid  = threadIdx.x;
  const int lane = tid & 63;
  const int wave = tid >> 6;
  const int nbn = N / BN;
  // bijective XCD swizzle (grid % 8 == 0 for all our launches)
  const int nwg = gridDim.x;
  const int wg  = (blockIdx.x & 7) * (nwg >> 3) + (blockIdx.x >> 3);
  const size_t m0 = (size_t)(wg / nbn) * BM;
  const size_t n0 = (size_t)(wg % nbn) * BN;

  // staging: wave w owns rows [w*32, w*32+32), 4 chunks of 8 rows.
  // global_load_lds writes lane l at ldsbase + l*16B -> row=l>>3, slot=l&7.
  // LDS content at (row,slot16) = A[m0+row][k0 + (slot^(row&7))*8]  (pre-swizzled source)
  const int srow  = lane >> 3;               // 0..7 (row within chunk; row&7 == srow)
  const int sslot = (lane & 7) ^ srow;       // pre-swizzled 16B slot within 128B row
  const u16* gA = A  + (m0 + wave*32 + srow) * KD + sslot * 8;
  const u16* gB = BT + (n0 + wave*32 + srow) * KD + sslot * 8;
  u16* lA = sA + (wave*32) * 64;             // 64 u16 per row
  u16* lB = sB + (wave*32) * 64;

  const int wm = (wave >> 1) * 64;
  const int wn = (wave & 1) * 64;
  f32x4 acc[4][4] = {};

  for (int kt = 0; kt < KD/BK; ++kt){
    const int k0 = kt * BK;
#pragma unroll
    for (int p = 0; p < 4; ++p){
      __builtin_amdgcn_global_load_lds(
          (const __attribute__((address_space(1))) void*)(gA + p*8*KD + k0),
          (__attribute__((address_space(3))) void*)(lA + p*8*64), 16, 0, 0);
      __builtin_amdgcn_global_load_lds(
          (const __attribute__((address_space(1))) void*)(gB + p*8*KD + k0),
          (__attribute__((address_space(3))) void*)(lB + p*8*64), 16, 0, 0);
    }
    __syncthreads();   // compiler drains vmcnt(0) before barrier
#pragma unroll
    for (int kk = 0; kk < 2; ++kk){
      short8 af[4], bfr[4];
      const int kidx = kk*4 + (lane >> 4);   // 16B k-chunk 0..7
#pragma unroll
      for (int i = 0; i < 4; ++i){
        const int arow = wm + i*16 + (lane & 15);
        af[i]  = *(const short8*)(sA + arow*64 + (kidx ^ (arow & 7)) * 8);
        const int brow = wn + i*16 + (lane & 15);
        bfr[i] = *(const short8*)(sB + brow*64 + (kidx ^ (brow & 7)) * 8);
      }
#pragma unroll
      for (int i = 0; i < 4; ++i)
#pragma unroll
        for (int j = 0; j < 4; ++j)
          acc[i][j] = __builtin_amdgcn_mfma_f32_16x16x32_bf16(af[i], bfr[j], acc[i][j], 0, 0, 0);
    }
    __syncthreads();
  }

  // epilogue: C/D mapping col=lane&15, row=(lane>>4)*4+r  [verified m89]
#pragma unroll
  for (int i = 0; i < 4; ++i){
    const int growb = wm + i*16 + (lane >> 4) * 4;
#pragma unroll
    for (int j = 0; j < 4; ++j){
      const size_t gcol = n0 + wn + j*16 + (lane & 15);
      float bv;
      if constexpr (MODE == 2)
        bv = (gcol < 1024) ? bias0[gcol] : (gcol < 2048) ? bias1[gcol - 1024] : bias2[gcol - 2048];
      else
        bv = bias0[gcol];
#pragma unroll
      for (int r = 0; r < 4; ++r){
        const size_t grow = m0 + growb + r;
        float v = acc[i][j][r] + bv;
        if constexpr (MODE == 0)      outB[grow * N + gcol] = f2bf(v);
        else if constexpr (MODE == 1) outB[grow * N + gcol] = f2bf(fmaxf(v, 0.0f));
        else                          outB[grow * N + gcol] = f2bf(gcol < 1024 ? v * 0.125f : v);
      }
    }
  }
}

// ---------------- per-token channel attention (wave-parallel, quad-masked) ----------------
// qkv[t][0:1024]=q(scaled) [1024:2048]=k [2048:3072]=v; per head 64 ch.
// One wave per (token,head); lane i = query channel. No max-subtraction
// (|q.k| small: q pre-scaled 1/8, LN'd activations -> exp safe in fp32; softmax
// shift-invariant). exp2 with log2e folded into q. Quad predicate
// (j0+3<=lane) + per-lane <=3-term fixup replaces per-j masking.
__global__ __launch_bounds__(256) void attn_chan(
    const u16* __restrict__ qkv, u16* __restrict__ av)
{
  __shared__ __align__(16) float2 skv[4][64];
  const int wid  = (blockIdx.x << 2) | (threadIdx.x >> 6);  // 0..8191
  const int lane = threadIdx.x & 63;
  float2* kw = skv[threadIdx.x >> 6];
  const int r = lane & 3;
  for (int pp = 0; pp < 8; ++pp){
    const int pair = wid * 8 + pp;              // 65536 (t,h) pairs
    const int t = pair >> 4, h = pair & 15;
    const size_t base = (size_t)t * 3072 + h * 64 + lane;
    const float qi2 = bf2f(qkv[base]) * 1.44269504f;   // log2(e) folded
    const float ki  = bf2f(qkv[base + 1024]);
    const float vi  = bf2f(qkv[base + 2048]);
    kw[lane] = make_float2(ki, vi);
    __syncthreads();
    float ssum = 0.0f, acc = 0.0f;
#pragma unroll 4
    for (int j0 = 0; j0 < 64; j0 += 4){
      const float4 ab = *(const float4*)(kw + j0);      // (k0,v0,k1,v1) broadcast
      const float4 cd = *(const float4*)(kw + j0 + 2);  // (k2,v2,k3,v3)
      float e0 = exp2f(qi2 * ab.x);
      float e1 = exp2f(qi2 * ab.z);
      float e2 = exp2f(qi2 * cd.x);
      float e3 = exp2f(qi2 * cd.z);
      const bool p = (j0 + 3 <= lane);                  // whole-quad predicate
      e0 = p ? e0 : 0.0f; e1 = p ? e1 : 0.0f;
      e2 = p ? e2 : 0.0f; e3 = p ? e3 : 0.0f;
      ssum += (e0 + e1) + (e2 + e3);
      acc = fmaf(e0, ab.y, fmaf(e1, ab.w, fmaf(e2, cd.y, fmaf(e3, cd.w, acc))));
    }
    // fixup: lanes with r<3 are missing j = lane-r .. lane (r+1 terms)
#pragma unroll
    for (int s = 0; s < 3; ++s){
      const float2 kv = kw[lane - r + s];
      float e = exp2f(qi2 * kv.x);
      e = (s <= r && r < 3) ? e : 0.0f;
      ssum += e;
      acc = fmaf(e, kv.y, acc);
    }
    av[(size_t)t * 1024 + h * 64 + lane] = f2bf(acc / ssum);
    __syncthreads();
  }
}

// ---------------- residual add + LayerNorm (row of 1024), y in bf16 ----------------
__global__ __launch_bounds__(256) void residual_ln(
    const u16* __restrict__ y, const float* xres,
    const float* __restrict__ gamma, const float* __restrict__ beta,
    float* xout, u16* __restrict__ xb)
{
  __shared__ float red[4];
  const int row = blockIdx.x, tid = threadIdx.x;
  const int lane = tid & 63, wave = tid >> 6;
  const ushort4 a = ((const ushort4*)(y + (size_t)row*DM))[tid];
  const float4  b = ((const float4*)(xres + (size_t)row*DM))[tid];
  float4 s; s.x=bf2f(a.x)+b.x; s.y=bf2f(a.y)+b.y; s.z=bf2f(a.z)+b.z; s.w=bf2f(a.w)+b.w;
  float p = s.x + s.y + s.z + s.w;
#pragma unroll
  for (int o = 32; o; o >>= 1) p += __shfl_xor(p, o);
  if (lane == 0) red[wave] = p;
  __syncthreads();
  const float mu = (red[0]+red[1]+red[2]+red[3]) * (1.0f/(float)DM);
  __syncthreads();
  const float dx=s.x-mu, dy=s.y-mu, dz=s.z-mu, dw=s.w-mu;
  float q2 = dx*dx + dy*dy + dz*dz + dw*dw;
#pragma unroll
  for (int o = 32; o; o >>= 1) q2 += __shfl_xor(q2, o);
  if (lane == 0) red[wave] = q2;
  __syncthreads();
  const float var = (red[0]+red[1]+red[2]+red[3]) * (1.0f/(float)DM);
  const float rstd = rsqrtf(var + 1e-5f);
  const float4 g  = ((const float4*)gamma)[tid];
  const float4 be = ((const float4*)beta)[tid];
  float4 o4;
  o4.x = dx*rstd*g.x + be.x;
  o4.y = dy*rstd*g.y + be.y;
  o4.z = dz*rstd*g.z + be.z;
  o4.w = dw*rstd*g.w + be.w;
  ((float4*)(xout + (size_t)row*DM))[tid] = o4;
  ushort4 ob; ob.x=f2bf(o4.x); ob.y=f2bf(o4.y); ob.z=f2bf(o4.z); ob.w=f2bf(o4.w);
  ((ushort4*)(xb + (size_t)row*DM))[tid] = ob;
}

// ---------------------------------------------------------------------------
extern "C" void kernel_launch(void* const* d_in, const int* in_sizes, int n_in,
                              void* d_out, int out_size, void* d_ws, size_t ws_size,
                              hipStream_t stream)
{
  const float* x    = (const float*)d_in[0];
  const float* Wq   = (const float*)d_in[1];
  const float* bq   = (const float*)d_in[2];
  const float* Wk   = (const float*)d_in[3];
  const float* bk   = (const float*)d_in[4];
  const float* Wv   = (const float*)d_in[5];
  const float* bv   = (const float*)d_in[6];
  const float* Wo   = (const float*)d_in[7];
  const float* bo   = (const float*)d_in[8];
  const float* W1   = (const float*)d_in[9];
  const float* b1   = (const float*)d_in[10];
  const float* W2   = (const float*)d_in[11];
  const float* b2   = (const float*)d_in[12];
  const float* gam  = (const float*)d_in[13];
  const float* bet  = (const float*)d_in[14];

  char* ws = (char*)d_ws;
  size_t off = 0;
  auto alloc = [&](size_t b){ void* p = ws + off; off = (off + b + 255) & ~(size_t)255; return p; };

  // probe whether 4-layer WT fits (deterministic per ws_size)
  const size_t oneWT = 6ull*1048576*2;
  const size_t rest  = ((size_t)TOK*DM*4)   // res
                     + ((size_t)TOK*DM*2)   // xb
                     + ((size_t)TOK*3072*2) // qkv
                     + ((size_t)TOK*DM*2)   // avb
                     + ((size_t)TOK*DM*2)   // hbuf
                     + ((size_t)TOK*DM*2)   // ybuf (bf16)
                     + 4096;                // alignment slack
  const bool all4 = (4*oneWT + rest) <= ws_size;

  u16*   WT   = (u16*)  alloc(all4 ? 4*oneWT : oneWT);
  float* res  = (float*)alloc((size_t)TOK*DM*4);
  u16*   xb   = (u16*)  alloc((size_t)TOK*DM*2);
  u16*   qkv  = (u16*)  alloc((size_t)TOK*3072*2);
  u16*   avb  = (u16*)  alloc((size_t)TOK*DM*2);
  u16*   hbuf = (u16*)  alloc((size_t)TOK*DM*2);
  u16*   ybuf = (u16*)  alloc((size_t)TOK*DM*2);
  if (off > ws_size) return;  // insufficient scratch -> fail loudly (poisoned d_out)

  posenc_add<<<TOK, 256, 0, stream>>>(x, res, xb);
  if (all4)
    transpose6<<<4*6*1024, 256, 0, stream>>>(Wq, Wk, Wv, Wo, W1, W2, WT, 0);

  for (int l = 0; l < 4; ++l){
    u16* wt = all4 ? (WT + (size_t)l * 6 * 1048576) : WT;
    if (!all4)
      transpose6<<<6*1024, 256, 0, stream>>>(Wq, Wk, Wv, Wo, W1, W2, WT, l);
    // q,k,v = x@W{q,k,v}+b (q pre-scaled by 1/8)
    gemm_k1024<2><<<(TOK/BM)*(3072/BN), 256, 0, stream>>>(
        xb, wt, bq + l*1024, bk + l*1024, bv + l*1024, qkv, TOK, 3072);
    attn_chan<<<2048, 256, 0, stream>>>(qkv, avb);
    // attn_out = av@Wo+bo -> bf16
    gemm_k1024<0><<<(TOK/BM)*(1024/BN), 256, 0, stream>>>(
        avb, wt + 3ull*1048576, bo + l*1024, nullptr, nullptr, ybuf, TOK, 1024);
    residual_ln<<<TOK, 256, 0, stream>>>(ybuf, res, gam + l*1024, bet + l*1024, res, xb);
    // h = relu(x@W1+b1) -> bf16
    gemm_k1024<1><<<(TOK/BM)*(1024/BN), 256, 0, stream>>>(
        xb, wt + 4ull*1048576, b1 + l*1024, nullptr, nullptr, hbuf, TOK, 1024);
    // y = h@W2+b2 -> bf16
    gemm_k1024<0><<<(TOK/BM)*(1024/BN), 256, 0, stream>>>(
        hbuf, wt + 5ull*1048576, b2 + l*1024, nullptr, nullptr, ybuf, TOK, 1024);
    float* xdst = (l == 3) ? (float*)d_out : res;
    residual_ln<<<TOK, 256, 0, stream>>>(ybuf, res, gam + l*1024, bet + l*1024, xdst, xb);
  }
}

// Round 6
// 763.881 us; speedup vs baseline: 1.1054x; 1.1054x over previous
//
#include <hip/hip_runtime.h>
#include <hip/hip_bf16.h>
#include <stdint.h>

// Encoder: B=2,S=2048,D=1024,HID=1024,NH=16,C=64,L=4. 4096 token-rows.
#define TOK 4096
#define DM  1024

using u16 = unsigned short;
typedef __attribute__((ext_vector_type(8))) short short8;   // bf16x8 frag (4 VGPR)
typedef __attribute__((ext_vector_type(4))) float f32x4;

__device__ __forceinline__ u16 f2bf(float f){
  unsigned u = __float_as_uint(f);
  return (u16)((u + 0x7fffu + ((u >> 16) & 1u)) >> 16);   // RNE
}
__device__ __forceinline__ float bf2f(u16 h){ return __uint_as_float(((unsigned)h) << 16); }

// ---------------- pos-enc add: r = x + pe, xb = bf16(r) ----------------
__global__ __launch_bounds__(256) void posenc_add(
    const float* __restrict__ x, float* __restrict__ r, u16* __restrict__ xb)
{
  const int t = blockIdx.x;          // token row 0..4095
  const int s = t & 2047;            // seq position
  const size_t base = (size_t)t * DM;
#pragma unroll
  for (int i = 0; i < 4; ++i){
    const int d = threadIdx.x + i * 256;
    const float e = (float)(d & ~1) * (1.0f / (float)DM);
    const float denom = powf(1000.0f, e);
    const float mat = (float)s / denom;
    const float pe = (d & 1) ? cosf(mat) : sinf(mat);
    const float v = x[base + d] + pe;
    r[base + d] = v;
    xb[base + d] = f2bf(v);
  }
}

// ---------- weight transpose+cast: 6 matrices [1024][1024] f32 -> [N][K] bf16 ----------
// WT layout per layer: [0]=WqT [1]=WkT [2]=WvT (contiguous 3072x1024) [3]=WoT [4]=W1T [5]=W2T
// Multi-layer launch: bid = (l-l0)*6144 + mm*1024 + t
__global__ __launch_bounds__(256) void transpose6(
    const float* __restrict__ Wq, const float* __restrict__ Wk, const float* __restrict__ Wv,
    const float* __restrict__ Wo, const float* __restrict__ W1, const float* __restrict__ W2,
    u16* __restrict__ WT, int l0)
{
  __shared__ float tile[32][33];
  const int bid = blockIdx.x;
  const int l  = l0 + bid / 6144;          // layer spans 6144 blocks
  const int mm = (bid >> 10) % 6;          // matrix 0..5 within layer
  const int t  = bid & 1023;
  const int tn = (t & 31) * 32;
  const int tk = (t >> 5) * 32;
  const float* src = (mm==0)?Wq:(mm==1)?Wk:(mm==2)?Wv:(mm==3)?Wo:(mm==4)?W1:W2;
  src += (size_t)l * 1048576;
  u16* dst = WT + ((size_t)(l - l0) * 6 + mm) * 1048576;
  const int tx = threadIdx.x & 31, ty = threadIdx.x >> 5;
#pragma unroll
  for (int i = 0; i < 4; ++i)
    tile[ty + i*8][tx] = src[(size_t)(tk + ty + i*8) * 1024 + tn + tx];
  __syncthreads();
#pragma unroll
  for (int i = 0; i < 4; ++i)
    dst[(size_t)(tn + ty + i*8) * 1024 + tk + tx] = f2bf(tile[tx][ty + i*8]);
}

// ---------------- bf16 MFMA GEMM: C[M][N] = A[M][1024] @ BT[N][1024]^T ----------------
// m97 structure: 128xBN tile, BK=64, single LDS buffer, global_load_lds(16B),
// pre-swizzled global source + swizzled ds_read. Bijective XCD swizzle on grid.
// BNt=128: 4 waves of 64x64 (acc 4x4). BNt=64: 4 waves of 64x32 (acc 4x2) --
// grid doubles to 512 for N=1024 => 2 blocks/CU, 2 waves/SIMD (occupancy fix).
// MODE 0: +bias -> bf16 ; MODE 1: relu(+bias) -> bf16 ; MODE 2: qkv (bias triple, q*=0.125) -> bf16
#define BM 128
#define BK 64
#define KD 1024

template<int MODE, int BNt>
__global__ __launch_bounds__(256) void gemm_k1024(
    const u16* __restrict__ A, const u16* __restrict__ BT,
    const float* __restrict__ bias0, const float* __restrict__ bias1, const float* __restrict__ bias2,
    u16* __restrict__ outB, int M, int N)
{
  constexpr int NFR = BNt / 32;             // 16-col n-fragments per wave (4 or 2)
  __shared__ __align__(16) u16 sA[BM*BK];   // linear rows of 128B; CONTENT swizzled
  __shared__ __align__(16) u16 sB[BNt*BK];
  const int tid  = threadIdx.x;
  const int lane = tid & 63;
  const int wave = tid >> 6;
  const int nbn = N / BNt;
  // bijective XCD swizzle (grid % 8 == 0 for all our launches)
  const int nwg = gridDim.x;
  const int wg  = (blockIdx.x & 7) * (nwg >> 3) + (blockIdx.x >> 3);
  const size_t m0 = (size_t)(wg / nbn) * BM;
  const size_t n0 = (size_t)(wg % nbn) * BNt;

  // staging: global_load_lds writes lane l at ldsbase + l*16B -> row=l>>3, slot=l&7.
  // LDS content at (row,slot16) = src[row][k0 + (slot^(row&7))*8]  (pre-swizzled source)
  const int srow  = lane >> 3;               // 0..7 (row within chunk; row&7 == srow)
  const int sslot = (lane & 7) ^ srow;       // pre-swizzled 16B slot within 128B row
  const u16* gA = A  + (m0 + wave*32 + srow) * KD + sslot * 8;          // 4 chunks/wave
  const u16* gB = BT + (n0 + wave*(BNt/4) + srow) * KD + sslot * 8;     // BNt/32 chunks/wave
  u16* lA = sA + (wave*32) * 64;             // 64 u16 per row
  u16* lB = sB + (wave*(BNt/4)) * 64;

  const int wm = (wave >> 1) * 64;
  const int wn = (wave & 1) * (BNt/2);
  f32x4 acc[4][NFR] = {};

  for (int kt = 0; kt < KD/BK; ++kt){
    const int k0 = kt * BK;
#pragma unroll
    for (int p = 0; p < 4; ++p)
      __builtin_amdgcn_global_load_lds(
          (const __attribute__((address_space(1))) void*)(gA + p*8*KD + k0),
          (__attribute__((address_space(3))) void*)(lA + p*8*64), 16, 0, 0);
#pragma unroll
    for (int p = 0; p < BNt/32; ++p)
      __builtin_amdgcn_global_load_lds(
          (const __attribute__((address_space(1))) void*)(gB + p*8*KD + k0),
          (__attribute__((address_space(3))) void*)(lB + p*8*64), 16, 0, 0);
    __syncthreads();   // compiler drains vmcnt(0) before barrier
#pragma unroll
    for (int kk = 0; kk < 2; ++kk){
      short8 af[4], bfr[NFR];
      const int kidx = kk*4 + (lane >> 4);   // 16B k-chunk 0..7
#pragma unroll
      for (int i = 0; i < 4; ++i){
        const int arow = wm + i*16 + (lane & 15);
        af[i]  = *(const short8*)(sA + arow*64 + (kidx ^ (arow & 7)) * 8);
      }
#pragma unroll
      for (int j = 0; j < NFR; ++j){
        const int brow = wn + j*16 + (lane & 15);
        bfr[j] = *(const short8*)(sB + brow*64 + (kidx ^ (brow & 7)) * 8);
      }
#pragma unroll
      for (int i = 0; i < 4; ++i)
#pragma unroll
        for (int j = 0; j < NFR; ++j)
          acc[i][j] = __builtin_amdgcn_mfma_f32_16x16x32_bf16(af[i], bfr[j], acc[i][j], 0, 0, 0);
    }
    __syncthreads();
  }

  // epilogue: C/D mapping col=lane&15, row=(lane>>4)*4+r  [verified m89]
#pragma unroll
  for (int i = 0; i < 4; ++i){
    const int growb = wm + i*16 + (lane >> 4) * 4;
#pragma unroll
    for (int j = 0; j < NFR; ++j){
      const size_t gcol = n0 + wn + j*16 + (lane & 15);
      float bv;
      if constexpr (MODE == 2)
        bv = (gcol < 1024) ? bias0[gcol] : (gcol < 2048) ? bias1[gcol - 1024] : bias2[gcol - 2048];
      else
        bv = bias0[gcol];
#pragma unroll
      for (int r = 0; r < 4; ++r){
        const size_t grow = m0 + growb + r;
        float v = acc[i][j][r] + bv;
        if constexpr (MODE == 0)      outB[grow * N + gcol] = f2bf(v);
        else if constexpr (MODE == 1) outB[grow * N + gcol] = f2bf(fmaxf(v, 0.0f));
        else                          outB[grow * N + gcol] = f2bf(gcol < 1024 ? v * 0.125f : v);
      }
    }
  }
}

// ---------------- per-token channel attention ----------------
// One (t,h) pair per wave, grid 16384 x 4 waves = 65536 pairs. NO barriers:
// each wave writes+reads only its own LDS slice (lgkmcnt ordering suffices).
// No max-subtraction (|q.k| <~ 1: q pre-scaled 1/8, LN'd inputs); exp2 with
// log2e folded into q; quad predicate + <=3-term fixup for the causal mask.
__global__ __launch_bounds__(256) void attn_chan(
    const u16* __restrict__ qkv, u16* __restrict__ av)
{
  __shared__ __align__(16) float2 skv[4][64];
  const int t    = blockIdx.x >> 2;
  const int hb   = blockIdx.x & 3;
  const int lane = threadIdx.x & 63;
  const int wave = threadIdx.x >> 6;
  const int h    = hb * 4 + wave;
  float2* kw = skv[wave];
  const int r = lane & 3;
  const size_t base = (size_t)t * 3072 + h * 64 + lane;
  const float qi2 = bf2f(qkv[base]) * 1.44269504f;   // log2(e) folded
  const float ki  = bf2f(qkv[base + 1024]);
  const float vi  = bf2f(qkv[base + 2048]);
  kw[lane] = make_float2(ki, vi);
  float ssum = 0.0f, acc = 0.0f;
#pragma unroll 4
  for (int j0 = 0; j0 < 64; j0 += 4){
    const float4 ab = *(const float4*)(kw + j0);      // (k0,v0,k1,v1) wave-private
    const float4 cd = *(const float4*)(kw + j0 + 2);  // (k2,v2,k3,v3)
    float e0 = exp2f(qi2 * ab.x);
    float e1 = exp2f(qi2 * ab.z);
    float e2 = exp2f(qi2 * cd.x);
    float e3 = exp2f(qi2 * cd.z);
    const bool p = (j0 + 3 <= lane);                  // whole-quad predicate
    e0 = p ? e0 : 0.0f; e1 = p ? e1 : 0.0f;
    e2 = p ? e2 : 0.0f; e3 = p ? e3 : 0.0f;
    ssum += (e0 + e1) + (e2 + e3);
    acc = fmaf(e0, ab.y, fmaf(e1, ab.w, fmaf(e2, cd.y, fmaf(e3, cd.w, acc))));
  }
  // fixup: lanes with r<3 are missing j = lane-r .. lane (r+1 terms)
#pragma unroll
  for (int s = 0; s < 3; ++s){
    const float2 kv = kw[lane - r + s];
    float e = exp2f(qi2 * kv.x);
    e = (s <= r && r < 3) ? e : 0.0f;
    ssum += e;
    acc = fmaf(e, kv.y, acc);
  }
  av[(size_t)t * 1024 + h * 64 + lane] = f2bf(acc / ssum);
}

// ---------------- residual add + LayerNorm (row of 1024), y in bf16 ----------------
__global__ __launch_bounds__(256) void residual_ln(
    const u16* __restrict__ y, const float* xres,
    const float* __restrict__ gamma, const float* __restrict__ beta,
    float* xout, u16* __restrict__ xb)
{
  __shared__ float red[4];
  const int row = blockIdx.x, tid = threadIdx.x;
  const int lane = tid & 63, wave = tid >> 6;
  const ushort4 a = ((const ushort4*)(y + (size_t)row*DM))[tid];
  const float4  b = ((const float4*)(xres + (size_t)row*DM))[tid];
  float4 s; s.x=bf2f(a.x)+b.x; s.y=bf2f(a.y)+b.y; s.z=bf2f(a.z)+b.z; s.w=bf2f(a.w)+b.w;
  float p = s.x + s.y + s.z + s.w;
#pragma unroll
  for (int o = 32; o; o >>= 1) p += __shfl_xor(p, o);
  if (lane == 0) red[wave] = p;
  __syncthreads();
  const float mu = (red[0]+red[1]+red[2]+red[3]) * (1.0f/(float)DM);
  __syncthreads();
  const float dx=s.x-mu, dy=s.y-mu, dz=s.z-mu, dw=s.w-mu;
  float q2 = dx*dx + dy*dy + dz*dz + dw*dw;
#pragma unroll
  for (int o = 32; o; o >>= 1) q2 += __shfl_xor(q2, o);
  if (lane == 0) red[wave] = q2;
  __syncthreads();
  const float var = (red[0]+red[1]+red[2]+red[3]) * (1.0f/(float)DM);
  const float rstd = rsqrtf(var + 1e-5f);
  const float4 g  = ((const float4*)gamma)[tid];
  const float4 be = ((const float4*)beta)[tid];
  float4 o4;
  o4.x = dx*rstd*g.x + be.x;
  o4.y = dy*rstd*g.y + be.y;
  o4.z = dz*rstd*g.z + be.z;
  o4.w = dw*rstd*g.w + be.w;
  ((float4*)(xout + (size_t)row*DM))[tid] = o4;
  ushort4 ob; ob.x=f2bf(o4.x); ob.y=f2bf(o4.y); ob.z=f2bf(o4.z); ob.w=f2bf(o4.w);
  ((ushort4*)(xb + (size_t)row*DM))[tid] = ob;
}

// ---------------------------------------------------------------------------
extern "C" void kernel_launch(void* const* d_in, const int* in_sizes, int n_in,
                              void* d_out, int out_size, void* d_ws, size_t ws_size,
                              hipStream_t stream)
{
  const float* x    = (const float*)d_in[0];
  const float* Wq   = (const float*)d_in[1];
  const float* bq   = (const float*)d_in[2];
  const float* Wk   = (const float*)d_in[3];
  const float* bk   = (const float*)d_in[4];
  const float* Wv   = (const float*)d_in[5];
  const float* bv   = (const float*)d_in[6];
  const float* Wo   = (const float*)d_in[7];
  const float* bo   = (const float*)d_in[8];
  const float* W1   = (const float*)d_in[9];
  const float* b1   = (const float*)d_in[10];
  const float* W2   = (const float*)d_in[11];
  const float* b2   = (const float*)d_in[12];
  const float* gam  = (const float*)d_in[13];
  const float* bet  = (const float*)d_in[14];

  char* ws = (char*)d_ws;
  size_t off = 0;
  auto alloc = [&](size_t b){ void* p = ws + off; off = (off + b + 255) & ~(size_t)255; return p; };

  // probe whether 4-layer WT fits (deterministic per ws_size)
  const size_t oneWT = 6ull*1048576*2;
  const size_t rest  = ((size_t)TOK*DM*4)   // res
                     + ((size_t)TOK*DM*2)   // xb
                     + ((size_t)TOK*3072*2) // qkv
                     + ((size_t)TOK*DM*2)   // avb
                     + ((size_t)TOK*DM*2)   // hbuf
                     + ((size_t)TOK*DM*2)   // ybuf (bf16)
                     + 4096;                // alignment slack
  const bool all4 = (4*oneWT + rest) <= ws_size;

  u16*   WT   = (u16*)  alloc(all4 ? 4*oneWT : oneWT);
  float* res  = (float*)alloc((size_t)TOK*DM*4);
  u16*   xb   = (u16*)  alloc((size_t)TOK*DM*2);
  u16*   qkv  = (u16*)  alloc((size_t)TOK*3072*2);
  u16*   avb  = (u16*)  alloc((size_t)TOK*DM*2);
  u16*   hbuf = (u16*)  alloc((size_t)TOK*DM*2);
  u16*   ybuf = (u16*)  alloc((size_t)TOK*DM*2);
  if (off > ws_size) return;  // insufficient scratch -> fail loudly (poisoned d_out)

  posenc_add<<<TOK, 256, 0, stream>>>(x, res, xb);
  if (all4)
    transpose6<<<4*6*1024, 256, 0, stream>>>(Wq, Wk, Wv, Wo, W1, W2, WT, 0);

  for (int l = 0; l < 4; ++l){
    u16* wt = all4 ? (WT + (size_t)l * 6 * 1048576) : WT;
    if (!all4)
      transpose6<<<6*1024, 256, 0, stream>>>(Wq, Wk, Wv, Wo, W1, W2, WT, l);
    // q,k,v = x@W{q,k,v}+b (q pre-scaled by 1/8)
    gemm_k1024<2,128><<<(TOK/BM)*(3072/128), 256, 0, stream>>>(
        xb, wt, bq + l*1024, bk + l*1024, bv + l*1024, qkv, TOK, 3072);
    attn_chan<<<TOK*4, 256, 0, stream>>>(qkv, avb);
    // attn_out = av@Wo+bo -> bf16   (BN=64: grid 512 = 2 blocks/CU)
    gemm_k1024<0,64><<<(TOK/BM)*(1024/64), 256, 0, stream>>>(
        avb, wt + 3ull*1048576, bo + l*1024, nullptr, nullptr, ybuf, TOK, 1024);
    residual_ln<<<TOK, 256, 0, stream>>>(ybuf, res, gam + l*1024, bet + l*1024, res, xb);
    // h = relu(x@W1+b1) -> bf16
    gemm_k1024<1,64><<<(TOK/BM)*(1024/64), 256, 0, stream>>>(
        xb, wt + 4ull*1048576, b1 + l*1024, nullptr, nullptr, hbuf, TOK, 1024);
    // y = h@W2+b2 -> bf16
    gemm_k1024<0,64><<<(TOK/BM)*(1024/64), 256, 0, stream>>>(
        hbuf, wt + 5ull*1048576, b2 + l*1024, nullptr, nullptr, ybuf, TOK, 1024);
    float* xdst = (l == 3) ? (float*)d_out : res;
    residual_ln<<<TOK, 256, 0, stream>>>(ybuf, res, gam + l*1024, bet + l*1024, xdst, xb);
  }
}

// Round 7
// 618.179 us; speedup vs baseline: 1.3660x; 1.2357x over previous
//
#include <hip/hip_runtime.h>
#include <hip/hip_bf16.h>
#include <stdint.h>

// Encoder: B=2,S=2048,D=1024,HID=1024,NH=16,C=64,L=4. 4096 token-rows.
#define TOK 4096
#define DM  1024

using u16 = unsigned short;
typedef __attribute__((ext_vector_type(8))) short short8;   // bf16x8 frag (4 VGPR)
typedef __attribute__((ext_vector_type(4))) float f32x4;

__device__ __forceinline__ u16 f2bf(float f){
  unsigned u = __float_as_uint(f);
  return (u16)((u + 0x7fffu + ((u >> 16) & 1u)) >> 16);   // RNE
}
__device__ __forceinline__ float bf2f(u16 h){ return __uint_as_float(((unsigned)h) << 16); }

// raw hardware exp2 (skip OCML guard code; |x| < ~40 here so bare op is exact
// enough, and 2^-200 flushes to 0 which implements the causal mask).
__device__ __forceinline__ float fexp2(float x){
#if __has_builtin(__builtin_amdgcn_exp2f)
  return __builtin_amdgcn_exp2f(x);
#else
  float r; asm("v_exp_f32 %0, %1\n\ts_nop 0" : "=v"(r) : "v"(x)); return r;
#endif
}

// ---------------- pos-enc add: r = x + pe, xb = bf16(r) ----------------
__global__ __launch_bounds__(256) void posenc_add(
    const float* __restrict__ x, float* __restrict__ r, u16* __restrict__ xb)
{
  const int t = blockIdx.x;          // token row 0..4095
  const int s = t & 2047;            // seq position
  const size_t base = (size_t)t * DM;
#pragma unroll
  for (int i = 0; i < 4; ++i){
    const int d = threadIdx.x + i * 256;
    const float e = (float)(d & ~1) * (1.0f / (float)DM);
    const float denom = powf(1000.0f, e);
    const float mat = (float)s / denom;
    const float pe = (d & 1) ? cosf(mat) : sinf(mat);
    const float v = x[base + d] + pe;
    r[base + d] = v;
    xb[base + d] = f2bf(v);
  }
}

// ---------- weight transpose+cast: 6 matrices [1024][1024] f32 -> [N][K] bf16 ----------
// WT layout per layer: [0]=WqT [1]=WkT [2]=WvT (contiguous 3072x1024) [3]=WoT [4]=W1T [5]=W2T
// Multi-layer launch: bid = (l-l0)*6144 + mm*1024 + t
__global__ __launch_bounds__(256) void transpose6(
    const float* __restrict__ Wq, const float* __restrict__ Wk, const float* __restrict__ Wv,
    const float* __restrict__ Wo, const float* __restrict__ W1, const float* __restrict__ W2,
    u16* __restrict__ WT, int l0)
{
  __shared__ float tile[32][33];
  const int bid = blockIdx.x;
  const int l  = l0 + bid / 6144;          // layer spans 6144 blocks
  const int mm = (bid >> 10) % 6;          // matrix 0..5 within layer
  const int t  = bid & 1023;
  const int tn = (t & 31) * 32;
  const int tk = (t >> 5) * 32;
  const float* src = (mm==0)?Wq:(mm==1)?Wk:(mm==2)?Wv:(mm==3)?Wo:(mm==4)?W1:W2;
  src += (size_t)l * 1048576;
  u16* dst = WT + ((size_t)(l - l0) * 6 + mm) * 1048576;
  const int tx = threadIdx.x & 31, ty = threadIdx.x >> 5;
#pragma unroll
  for (int i = 0; i < 4; ++i)
    tile[ty + i*8][tx] = src[(size_t)(tk + ty + i*8) * 1024 + tn + tx];
  __syncthreads();
#pragma unroll
  for (int i = 0; i < 4; ++i)
    dst[(size_t)(tn + ty + i*8) * 1024 + tk + tx] = f2bf(tile[tx][ty + i*8]);
}

// ---------------- bf16 MFMA GEMM: C[M][N] = A[M][1024] @ BT[N][1024]^T ----------------
// m97 structure: 128xBN tile, BK=64, single LDS buffer, global_load_lds(16B),
// pre-swizzled global source + swizzled ds_read. Bijective XCD swizzle on grid.
// BNt=128: 4 waves of 64x64 (acc 4x4). BNt=64: 4 waves of 64x32 (acc 4x2) --
// grid doubles to 512 for N=1024 => 2 blocks/CU, 2 waves/SIMD (occupancy fix).
// MODE 0: +bias -> bf16 ; MODE 1: relu(+bias) -> bf16 ; MODE 2: qkv (bias triple, q*=0.125) -> bf16
#define BM 128
#define BK 64
#define KD 1024

template<int MODE, int BNt>
__global__ __launch_bounds__(256) void gemm_k1024(
    const u16* __restrict__ A, const u16* __restrict__ BT,
    const float* __restrict__ bias0, const float* __restrict__ bias1, const float* __restrict__ bias2,
    u16* __restrict__ outB, int M, int N)
{
  constexpr int NFR = BNt / 32;             // 16-col n-fragments per wave (4 or 2)
  __shared__ __align__(16) u16 sA[BM*BK];   // linear rows of 128B; CONTENT swizzled
  __shared__ __align__(16) u16 sB[BNt*BK];
  const int tid  = threadIdx.x;
  const int lane = tid & 63;
  const int wave = tid >> 6;
  const int nbn = N / BNt;
  // bijective XCD swizzle (grid % 8 == 0 for all our launches)
  const int nwg = gridDim.x;
  const int wg  = (blockIdx.x & 7) * (nwg >> 3) + (blockIdx.x >> 3);
  const size_t m0 = (size_t)(wg / nbn) * BM;
  const size_t n0 = (size_t)(wg % nbn) * BNt;

  // staging: global_load_lds writes lane l at ldsbase + l*16B -> row=l>>3, slot=l&7.
  // LDS content at (row,slot16) = src[row][k0 + (slot^(row&7))*8]  (pre-swizzled source)
  const int srow  = lane >> 3;               // 0..7 (row within chunk; row&7 == srow)
  const int sslot = (lane & 7) ^ srow;       // pre-swizzled 16B slot within 128B row
  const u16* gA = A  + (m0 + wave*32 + srow) * KD + sslot * 8;          // 4 chunks/wave
  const u16* gB = BT + (n0 + wave*(BNt/4) + srow) * KD + sslot * 8;     // BNt/32 chunks/wave
  u16* lA = sA + (wave*32) * 64;             // 64 u16 per row
  u16* lB = sB + (wave*(BNt/4)) * 64;

  const int wm = (wave >> 1) * 64;
  const int wn = (wave & 1) * (BNt/2);
  f32x4 acc[4][NFR] = {};

  for (int kt = 0; kt < KD/BK; ++kt){
    const int k0 = kt * BK;
#pragma unroll
    for (int p = 0; p < 4; ++p)
      __builtin_amdgcn_global_load_lds(
          (const __attribute__((address_space(1))) void*)(gA + p*8*KD + k0),
          (__attribute__((address_space(3))) void*)(lA + p*8*64), 16, 0, 0);
#pragma unroll
    for (int p = 0; p < BNt/32; ++p)
      __builtin_amdgcn_global_load_lds(
          (const __attribute__((address_space(1))) void*)(gB + p*8*KD + k0),
          (__attribute__((address_space(3))) void*)(lB + p*8*64), 16, 0, 0);
    __syncthreads();   // compiler drains vmcnt(0) before barrier
#pragma unroll
    for (int kk = 0; kk < 2; ++kk){
      short8 af[4], bfr[NFR];
      const int kidx = kk*4 + (lane >> 4);   // 16B k-chunk 0..7
#pragma unroll
      for (int i = 0; i < 4; ++i){
        const int arow = wm + i*16 + (lane & 15);
        af[i]  = *(const short8*)(sA + arow*64 + (kidx ^ (arow & 7)) * 8);
      }
#pragma unroll
      for (int j = 0; j < NFR; ++j){
        const int brow = wn + j*16 + (lane & 15);
        bfr[j] = *(const short8*)(sB + brow*64 + (kidx ^ (brow & 7)) * 8);
      }
#pragma unroll
      for (int i = 0; i < 4; ++i)
#pragma unroll
        for (int j = 0; j < NFR; ++j)
          acc[i][j] = __builtin_amdgcn_mfma_f32_16x16x32_bf16(af[i], bfr[j], acc[i][j], 0, 0, 0);
    }
    __syncthreads();
  }

  // epilogue: C/D mapping col=lane&15, row=(lane>>4)*4+r  [verified m89]
#pragma unroll
  for (int i = 0; i < 4; ++i){
    const int growb = wm + i*16 + (lane >> 4) * 4;
#pragma unroll
    for (int j = 0; j < NFR; ++j){
      const size_t gcol = n0 + wn + j*16 + (lane & 15);
      float bv;
      if constexpr (MODE == 2)
        bv = (gcol < 1024) ? bias0[gcol] : (gcol < 2048) ? bias1[gcol - 1024] : bias2[gcol - 2048];
      else
        bv = bias0[gcol];
#pragma unroll
      for (int r = 0; r < 4; ++r){
        const size_t grow = m0 + growb + r;
        float v = acc[i][j][r] + bv;
        if constexpr (MODE == 0)      outB[grow * N + gcol] = f2bf(v);
        else if constexpr (MODE == 1) outB[grow * N + gcol] = f2bf(fmaxf(v, 0.0f));
        else                          outB[grow * N + gcol] = f2bf(gcol < 1024 ? v * 0.125f : v);
      }
    }
  }
}

// ---------------- per-token channel attention ----------------
// One (t,h) pair per wave, grid 16384 x 4 waves. NO barriers (wave-private LDS
// slice). No max-subtraction (|q.k| <~ 1). Raw v_exp_f32 via fexp2 (OCML guard
// removed -- this was the round-6 regression). Causal mask folded into the exp
// argument as a per-quad bias: exp2(qk - 200) == 0 exactly.
__global__ __launch_bounds__(256) void attn_chan(
    const u16* __restrict__ qkv, u16* __restrict__ av)
{
  __shared__ __align__(16) float2 skv[4][64];
  const int t    = blockIdx.x >> 2;
  const int hb   = blockIdx.x & 3;
  const int lane = threadIdx.x & 63;
  const int wave = threadIdx.x >> 6;
  const int h    = hb * 4 + wave;
  float2* kw = skv[wave];
  const int r = lane & 3;
  const size_t base = (size_t)t * 3072 + h * 64 + lane;
  const float qi2 = bf2f(qkv[base]) * 1.44269504f;   // log2(e) folded
  const float ki  = bf2f(qkv[base + 1024]);
  const float vi  = bf2f(qkv[base + 2048]);
  kw[lane] = make_float2(ki, vi);
  float ssum = 0.0f, acc = 0.0f;
#pragma unroll 8
  for (int j0 = 0; j0 < 64; j0 += 4){
    const float4 ab = *(const float4*)(kw + j0);      // (k0,v0,k1,v1) wave-private
    const float4 cd = *(const float4*)(kw + j0 + 2);  // (k2,v2,k3,v3)
    const float bias = (j0 + 3 <= lane) ? 0.0f : -200.0f;  // whole-quad causal mask
    const float e0 = fexp2(fmaf(qi2, ab.x, bias));
    const float e1 = fexp2(fmaf(qi2, ab.z, bias));
    const float e2 = fexp2(fmaf(qi2, cd.x, bias));
    const float e3 = fexp2(fmaf(qi2, cd.z, bias));
    ssum += (e0 + e1) + (e2 + e3);
    acc = fmaf(e0, ab.y, acc);
    acc = fmaf(e1, ab.w, acc);
    acc = fmaf(e2, cd.y, acc);
    acc = fmaf(e3, cd.w, acc);
  }
  // fixup: lanes with r<3 are missing j = lane-r .. lane (r+1 terms)
#pragma unroll
  for (int s = 0; s < 3; ++s){
    const float2 kv = kw[lane - r + s];
    const float bf = (s <= r && r < 3) ? 0.0f : -200.0f;
    const float e = fexp2(fmaf(qi2, kv.x, bf));
    ssum += e;
    acc = fmaf(e, kv.y, acc);
  }
  av[(size_t)t * 1024 + h * 64 + lane] = f2bf(acc / ssum);
}

// ---------------- residual add + LayerNorm (row of 1024), y in bf16 ----------------
__global__ __launch_bounds__(256) void residual_ln(
    const u16* __restrict__ y, const float* xres,
    const float* __restrict__ gamma, const float* __restrict__ beta,
    float* xout, u16* __restrict__ xb)
{
  __shared__ float red[4];
  const int row = blockIdx.x, tid = threadIdx.x;
  const int lane = tid & 63, wave = tid >> 6;
  const ushort4 a = ((const ushort4*)(y + (size_t)row*DM))[tid];
  const float4  b = ((const float4*)(xres + (size_t)row*DM))[tid];
  float4 s; s.x=bf2f(a.x)+b.x; s.y=bf2f(a.y)+b.y; s.z=bf2f(a.z)+b.z; s.w=bf2f(a.w)+b.w;
  float p = s.x + s.y + s.z + s.w;
#pragma unroll
  for (int o = 32; o; o >>= 1) p += __shfl_xor(p, o);
  if (lane == 0) red[wave] = p;
  __syncthreads();
  const float mu = (red[0]+red[1]+red[2]+red[3]) * (1.0f/(float)DM);
  __syncthreads();
  const float dx=s.x-mu, dy=s.y-mu, dz=s.z-mu, dw=s.w-mu;
  float q2 = dx*dx + dy*dy + dz*dz + dw*dw;
#pragma unroll
  for (int o = 32; o; o >>= 1) q2 += __shfl_xor(q2, o);
  if (lane == 0) red[wave] = q2;
  __syncthreads();
  const float var = (red[0]+red[1]+red[2]+red[3]) * (1.0f/(float)DM);
  const float rstd = rsqrtf(var + 1e-5f);
  const float4 g  = ((const float4*)gamma)[tid];
  const float4 be = ((const float4*)beta)[tid];
  float4 o4;
  o4.x = dx*rstd*g.x + be.x;
  o4.y = dy*rstd*g.y + be.y;
  o4.z = dz*rstd*g.z + be.z;
  o4.w = dw*rstd*g.w + be.w;
  ((float4*)(xout + (size_t)row*DM))[tid] = o4;
  ushort4 ob; ob.x=f2bf(o4.x); ob.y=f2bf(o4.y); ob.z=f2bf(o4.z); ob.w=f2bf(o4.w);
  ((ushort4*)(xb + (size_t)row*DM))[tid] = ob;
}

// ---------------------------------------------------------------------------
extern "C" void kernel_launch(void* const* d_in, const int* in_sizes, int n_in,
                              void* d_out, int out_size, void* d_ws, size_t ws_size,
                              hipStream_t stream)
{
  const float* x    = (const float*)d_in[0];
  const float* Wq   = (const float*)d_in[1];
  const float* bq   = (const float*)d_in[2];
  const float* Wk   = (const float*)d_in[3];
  const float* bk   = (const float*)d_in[4];
  const float* Wv   = (const float*)d_in[5];
  const float* bv   = (const float*)d_in[6];
  const float* Wo   = (const float*)d_in[7];
  const float* bo   = (const float*)d_in[8];
  const float* W1   = (const float*)d_in[9];
  const float* b1   = (const float*)d_in[10];
  const float* W2   = (const float*)d_in[11];
  const float* b2   = (const float*)d_in[12];
  const float* gam  = (const float*)d_in[13];
  const float* bet  = (const float*)d_in[14];

  char* ws = (char*)d_ws;
  size_t off = 0;
  auto alloc = [&](size_t b){ void* p = ws + off; off = (off + b + 255) & ~(size_t)255; return p; };

  // probe whether 4-layer WT fits (deterministic per ws_size)
  const size_t oneWT = 6ull*1048576*2;
  const size_t rest  = ((size_t)TOK*DM*4)   // res
                     + ((size_t)TOK*DM*2)   // xb
                     + ((size_t)TOK*3072*2) // qkv
                     + ((size_t)TOK*DM*2)   // avb
                     + ((size_t)TOK*DM*2)   // hbuf
                     + ((size_t)TOK*DM*2)   // ybuf (bf16)
                     + 4096;                // alignment slack
  const bool all4 = (4*oneWT + rest) <= ws_size;

  u16*   WT   = (u16*)  alloc(all4 ? 4*oneWT : oneWT);
  float* res  = (float*)alloc((size_t)TOK*DM*4);
  u16*   xb   = (u16*)  alloc((size_t)TOK*DM*2);
  u16*   qkv  = (u16*)  alloc((size_t)TOK*3072*2);
  u16*   avb  = (u16*)  alloc((size_t)TOK*DM*2);
  u16*   hbuf = (u16*)  alloc((size_t)TOK*DM*2);
  u16*   ybuf = (u16*)  alloc((size_t)TOK*DM*2);
  if (off > ws_size) return;  // insufficient scratch -> fail loudly (poisoned d_out)

  posenc_add<<<TOK, 256, 0, stream>>>(x, res, xb);
  if (all4)
    transpose6<<<4*6*1024, 256, 0, stream>>>(Wq, Wk, Wv, Wo, W1, W2, WT, 0);

  for (int l = 0; l < 4; ++l){
    u16* wt = all4 ? (WT + (size_t)l * 6 * 1048576) : WT;
    if (!all4)
      transpose6<<<6*1024, 256, 0, stream>>>(Wq, Wk, Wv, Wo, W1, W2, WT, l);
    // q,k,v = x@W{q,k,v}+b (q pre-scaled by 1/8)
    gemm_k1024<2,128><<<(TOK/BM)*(3072/128), 256, 0, stream>>>(
        xb, wt, bq + l*1024, bk + l*1024, bv + l*1024, qkv, TOK, 3072);
    attn_chan<<<TOK*4, 256, 0, stream>>>(qkv, avb);
    // attn_out = av@Wo+bo -> bf16   (BN=64: grid 512 = 2 blocks/CU)
    gemm_k1024<0,64><<<(TOK/BM)*(1024/64), 256, 0, stream>>>(
        avb, wt + 3ull*1048576, bo + l*1024, nullptr, nullptr, ybuf, TOK, 1024);
    residual_ln<<<TOK, 256, 0, stream>>>(ybuf, res, gam + l*1024, bet + l*1024, res, xb);
    // h = relu(x@W1+b1) -> bf16
    gemm_k1024<1,64><<<(TOK/BM)*(1024/64), 256, 0, stream>>>(
        xb, wt + 4ull*1048576, b1 + l*1024, nullptr, nullptr, hbuf, TOK, 1024);
    // y = h@W2+b2 -> bf16
    gemm_k1024<0,64><<<(TOK/BM)*(1024/64), 256, 0, stream>>>(
        hbuf, wt + 5ull*1048576, b2 + l*1024, nullptr, nullptr, ybuf, TOK, 1024);
    float* xdst = (l == 3) ? (float*)d_out : res;
    residual_ln<<<TOK, 256, 0, stream>>>(ybuf, res, gam + l*1024, bet + l*1024, xdst, xb);
  }
}